// Round 1
// baseline (2049.387 us; speedup 1.0000x reference)
//
#include <hip/hip_runtime.h>
#include <cstdint>
#include <cstddef>

#pragma clang fp contract(off)

#define N_ANCH 2359296
#define N_POS  262144
#define N_A    9
#define K_PRE  12000
#define K_POST 2000
#define NWORD  188
#define NCAND_PAD 12032
#define TIE_CAP 65536

typedef unsigned int u32;
typedef unsigned long long u64;

// anchors from _generate_anchors(): base 16, ratios {0.5,1,2} (outer), scales {8,16,32}
__constant__ float c_anch[9][4] = {
  { -84.f,  -40.f,   99.f,   55.f },
  { -176.f, -88.f,  191.f,  103.f },
  { -360.f, -184.f, 375.f,  199.f },
  { -56.f,  -56.f,   71.f,   71.f },
  { -120.f, -120.f, 135.f,  135.f },
  { -248.f, -248.f, 263.f,  263.f },
  { -36.f,  -80.f,   51.f,   95.f },
  { -80.f,  -168.f,  95.f,  183.f },
  { -168.f, -344.f, 183.f,  359.f },
};

// Replica of XLA:CPU GenerateVF32Exp (Cephes/Eigen expf), UNFUSED mul/add.
__device__ __forceinline__ float pexpf(float xin) {
#pragma clang fp contract(off)
  const float exp_hi = 88.3762626647950f;
  const float exp_lo = -88.3762626647949f;
  const float LOG2EF = 1.44269504088896341f;
  const float C1 = 0.693359375f;
  const float C2 = -2.12194440e-4f;
  const float p0 = 1.9875691500E-4f;
  const float p1 = 1.3981999507E-3f;
  const float p2 = 8.3334519073E-3f;
  const float p3 = 4.1665795894E-2f;
  const float p4 = 1.6666665459E-1f;
  const float p5 = 5.0000001201E-1f;
  float x = fminf(fmaxf(xin, exp_lo), exp_hi);
  float fx = floorf(x * LOG2EF + 0.5f);
  float tmp = C1 * fx;
  float z = C2 * fx;
  x = x - tmp;
  x = x - z;
  z = x * x;
  float y = x * p0 + p1;
  y = y * x + p2;
  y = y * x + p3;
  y = y * x + p4;
  y = y * x + p5;
  y = y * z + x;
  y = 1.0f + y;
  int n = (int)fx;
  u32 e = ((u32)(n + 127)) << 23;
  return y * __uint_as_float(e);
}

// Box decode, bit-matching the reference arithmetic order.
__device__ __forceinline__ void decode_box(const float* __restrict__ bbox, int aidx,
                                           float4* ob, float* oarea, bool* okeep) {
#pragma clang fp contract(off)
  int pos = aidx / 9;
  int a = aidx - pos * 9;
  int w = pos & 511;
  int h = pos >> 9;
  float shx = (float)(w * 8);
  float shy = (float)(h * 8);
  float ax1 = c_anch[a][0] + shx;
  float ay1 = c_anch[a][1] + shy;
  float ax2 = c_anch[a][2] + shx;
  float ay2 = c_anch[a][3] + shy;
  float aw = (ax2 - ax1) + 1.0f;
  float ah = (ay2 - ay1) + 1.0f;
  float acx = ax1 + 0.5f * aw;
  float acy = ay1 + 0.5f * ah;
  const float* d = bbox + (size_t)pos * 36 + (size_t)a * 4;
  float dx = d[0], dy = d[1], dw = d[2], dh = d[3];
  float pcx = dx * aw + acx;
  float pcy = dy * ah + acy;
  float pw = pexpf(dw) * aw;
  float ph = pexpf(dh) * ah;
  float x1 = pcx - 0.5f * pw;
  float y1 = pcy - 0.5f * ph;
  float x2 = pcx + 0.5f * pw;
  float y2 = pcy + 0.5f * ph;
  x1 = fminf(fmaxf(x1, 0.0f), 4095.0f);
  y1 = fminf(fmaxf(y1, 0.0f), 4095.0f);
  x2 = fminf(fmaxf(x2, 0.0f), 4095.0f);
  y2 = fminf(fmaxf(y2, 0.0f), 4095.0f);
  *ob = make_float4(x1, y1, x2, y2);
  float ww = (x2 - x1) + 1.0f;
  float hh = (y2 - y1) + 1.0f;
  *oarea = ww * hh;
  *okeep = (ww >= 16.0f) && (hh >= 16.0f);
}

// Stage A: per-anchor softmax prob -> sortable key (0 if min-size filtered).
__global__ void k_scores(const float* __restrict__ cls, const float* __restrict__ bbox,
                         u32* __restrict__ keys) {
#pragma clang fp contract(off)
  int t = blockIdx.x * blockDim.x + threadIdx.x;
  if (t >= N_ANCH) return;
  int pos = t / 9;
  int a = t - pos * 9;
  float s0 = cls[(size_t)pos * 18 + a];
  float s1 = cls[(size_t)pos * 18 + 9 + a];
  float m = fmaxf(s0, s1);
  float e0 = pexpf(s0 - m);
  float e1 = pexpf(s1 - m);
  float p = e1 / (e0 + e1);
  float4 box; float area; bool km;
  decode_box(bbox, t, &box, &area, &km);
  keys[t] = km ? (__float_as_uint(p) | 0x80000000u) : 0u;
}

__global__ void k_ctl_init(u32* ctl, u32* hist) {
  int t = threadIdx.x;
  if (t < 16) ctl[t] = (t == 1) ? (u32)K_PRE : 0u;
  if (t < 256) hist[t] = 0u;
}

__global__ void k_hist(const u32* __restrict__ keys, const u32* __restrict__ ctl,
                       u32* __restrict__ hist, int shift) {
  __shared__ u32 lh[256];
  lh[threadIdx.x] = 0u;
  __syncthreads();
  u32 prefix = ctl[0];
  u32 msk = (shift == 24) ? 0u : (0xFFFFFFFFu << (shift + 8));
  int stride = gridDim.x * blockDim.x;
  for (int i = blockIdx.x * blockDim.x + threadIdx.x; i < N_ANCH; i += stride) {
    u32 k = keys[i];
    if ((k & msk) == prefix) atomicAdd(&lh[(k >> shift) & 0xFFu], 1u);
  }
  __syncthreads();
  atomicAdd(&hist[threadIdx.x], lh[threadIdx.x]);
}

__global__ void k_scan(u32* ctl, u32* hist, int shift) {
  if (threadIdx.x != 0) return;
  u32 krem = ctl[1];
  u32 cum = 0;
  int d = 255;
  for (; d >= 0; --d) {
    u32 c = hist[d];
    if (cum + c >= krem) break;
    cum += c;
  }
  if (d < 0) d = 0;
  ctl[0] |= ((u32)d) << shift;
  ctl[1] = krem - cum;
  if (shift == 0) { ctl[2] = ctl[0]; ctl[3] = ctl[1]; }
  for (int i = 0; i < 256; ++i) hist[i] = 0u;
}

__global__ void k_collect(const u32* __restrict__ keys, u32* __restrict__ ctl,
                          int* __restrict__ sel, int* __restrict__ tie) {
  u32 kstar = ctl[2];
  int stride = gridDim.x * blockDim.x;
  for (int i = blockIdx.x * blockDim.x + threadIdx.x; i < N_ANCH; i += stride) {
    u32 k = keys[i];
    if (k > kstar) {
      u32 p = atomicAdd(&ctl[4], 1u);
      sel[p] = i;
    } else if (k == kstar) {
      u32 p = atomicAdd(&ctl[5], 1u);
      if (p < TIE_CAP) tie[p] = i;
    }
  }
}

__global__ void k_tiepick(const u32* __restrict__ ctl, const int* __restrict__ tie,
                          int* __restrict__ sel) {
  u32 T = ctl[5]; if (T > TIE_CAP) T = TIE_CAP;
  if (T > 8192u) T = 8192u;  // safety; tie sets are tiny in practice
  u32 need = ctl[3];
  u32 base = ctl[4];
  for (u32 t = threadIdx.x; t < T; t += blockDim.x) {
    int v = tie[t];
    u32 r = 0;
    for (u32 u = 0; u < T; ++u) r += (tie[u] < v) ? 1u : 0u;
    if (r < need) sel[base + r] = v;
  }
}

__global__ void k_build(const u32* __restrict__ keys, const int* __restrict__ sel,
                        u64* __restrict__ comps) {
  int t = blockIdx.x * blockDim.x + threadIdx.x;
  if (t >= K_PRE) return;
  int idx = sel[t];
  u64 key = (u64)keys[idx];
  comps[t] = (key << 32) | (u64)(0xFFFFFFFFu - (u32)idx);
}

// O(K^2) rank sort: comp descending == (score desc, index asc) == lax.top_k order
__global__ void k_rank(const u64* __restrict__ comps, const int* __restrict__ sel,
                       int* __restrict__ ordIdx) {
  int t = blockIdx.x * blockDim.x + threadIdx.x;
  if (t >= K_PRE) return;
  u64 c = comps[t];
  int cnt = 0;
#pragma unroll 8
  for (int j = 0; j < K_PRE; ++j) cnt += (comps[j] > c) ? 1 : 0;
  ordIdx[cnt] = sel[t];
}

__global__ void k_decode(const float* __restrict__ bbox, const int* __restrict__ ordIdx,
                         float4* __restrict__ props, float* __restrict__ areas) {
  int t = blockIdx.x * blockDim.x + threadIdx.x;
  if (t >= K_PRE) return;
  float4 box; float area; bool km;
  decode_box(bbox, ordIdx[t], &box, &area, &km);
  props[t] = box;
  areas[t] = area;
}

__global__ void k_mask(const float4* __restrict__ props, const float* __restrict__ areas,
                       u64* __restrict__ mask) {
#pragma clang fp contract(off)
  __shared__ float4 bj[64];
  __shared__ float aj[64];
  int wj = blockIdx.y;
  int j0 = wj * 64;
  int jt = j0 + threadIdx.x;
  bj[threadIdx.x] = props[jt];   // rows >= 12000 are stale but masked below
  aj[threadIdx.x] = areas[jt];
  __syncthreads();
  int i = blockIdx.x * 64 + threadIdx.x;
  float4 bi = props[i];
  float ai = areas[i];
  u64 bits = 0;
  for (int jj = 0; jj < 64; ++jj) {
    int j = j0 + jj;
    float4 bb = bj[jj];
    float xx1 = fmaxf(bi.x, bb.x);
    float yy1 = fmaxf(bi.y, bb.y);
    float xx2 = fminf(bi.z, bb.z);
    float yy2 = fminf(bi.w, bb.w);
    float w = fmaxf(0.0f, (xx2 - xx1) + 1.0f);
    float h = fmaxf(0.0f, (yy2 - yy1) + 1.0f);
    float inter = w * h;
    float iou = inter / ((ai + aj[jj]) - inter);
    if ((iou > 0.7f) && (j < K_PRE)) bits |= (1ull << jj);
  }
  mask[(size_t)i * NWORD + wj] = bits;
}

// Serial greedy NMS, single wave; suppression bitset lives in registers (3 u64/lane).
__global__ void k_nms(const u64* __restrict__ mask, int* __restrict__ keep) {
  int lane = threadIdx.x;
  int w0 = lane, w1 = lane + 64, w2 = lane + 128;
  u64 v0 = ~0ull;
  u64 v1 = ~0ull;
  u64 v2 = (w2 < NWORD - 1) ? ~0ull : ((w2 == NWORD - 1) ? 0xFFFFFFFFull : 0ull);
  u64 rem0 = 0, rem1 = 0, rem2 = 0;
  int nk = 0;
  while (nk < K_POST) {
    u64 a0 = ~rem0 & v0;
    u64 a1 = ~rem1 & v1;
    u64 a2 = ~rem2 & v2;
    int c0 = a0 ? (w0 * 64 + (int)__builtin_ctzll(a0)) : 0x7FFFFFFF;
    int c1 = a1 ? (w1 * 64 + (int)__builtin_ctzll(a1)) : 0x7FFFFFFF;
    int c2 = a2 ? (w2 * 64 + (int)__builtin_ctzll(a2)) : 0x7FFFFFFF;
    int best = min(c0, min(c1, c2));
    for (int off = 32; off > 0; off >>= 1) best = min(best, __shfl_xor(best, off));
    if (best >= 0x7FFFFFFF) break;
    if (lane == 0) keep[nk] = best;
    nk++;
    const u64* row = mask + (size_t)best * NWORD;
    rem0 |= row[w0];
    rem1 |= row[w1];
    if (w2 < NWORD) rem2 |= row[w2];
  }
  // exhausted: reference argmax over all -inf returns index 0
  for (int t = nk + lane; t < K_POST; t += 64) keep[t] = 0;
}

__global__ void k_out(const int* __restrict__ keep, const float4* __restrict__ props,
                      float* __restrict__ out) {
  int t = blockIdx.x * blockDim.x + threadIdx.x;
  if (t >= K_POST) return;
  float4 b = props[keep[t]];
  out[t * 5 + 0] = 0.0f;
  out[t * 5 + 1] = b.x;
  out[t * 5 + 2] = b.y;
  out[t * 5 + 3] = b.z;
  out[t * 5 + 4] = b.w;
}

extern "C" void kernel_launch(void* const* d_in, const int* in_sizes, int n_in,
                              void* d_out, int out_size, void* d_ws, size_t ws_size,
                              hipStream_t stream) {
  const float* cls  = (const float*)d_in[0];
  const float* bbox = (const float*)d_in[1];
  float* out = (float*)d_out;
  char* ws = (char*)d_ws;

  // Layout (mask overlays keys/ctl/hist/sel/tie, all dead before k_mask):
  // [0, 18096128)          mask u64[12032*188]   (also keys u32[N] in [0, 9437184))
  // [9437184, +64)         ctl u32[16]
  // [9437248, +1024)       hist u32[256]
  // [9438464, +48128)      sel i32[12032]
  // [9486592, +262144)     tie i32[65536]
  // [18096128, +96256)     comps u64[12032]
  // [18192384, +48128)     ordIdx i32[12032]
  // [18240512, +192512)    props float4[12032]
  // [18433024, +48128)     areas f32[12032]
  // [18481152, +8192)      keep i32[2048]
  u64* mask    = (u64*)ws;
  u32* keys    = (u32*)ws;
  u32* ctl     = (u32*)(ws + 9437184);
  u32* hist    = (u32*)(ws + 9437248);
  int* sel     = (int*)(ws + 9438464);
  int* tie     = (int*)(ws + 9486592);
  u64* comps   = (u64*)(ws + 18096128);
  int* ordIdx  = (int*)(ws + 18192384);
  float4* props= (float4*)(ws + 18240512);
  float* areas = (float*)(ws + 18433024);
  int* keep    = (int*)(ws + 18481152);

  k_scores<<<dim3((N_ANCH + 255) / 256), dim3(256), 0, stream>>>(cls, bbox, keys);
  k_ctl_init<<<dim3(1), dim3(256), 0, stream>>>(ctl, hist);
  const int shifts[4] = {24, 16, 8, 0};
  for (int s = 0; s < 4; ++s) {
    k_hist<<<dim3(1024), dim3(256), 0, stream>>>(keys, ctl, hist, shifts[s]);
    k_scan<<<dim3(1), dim3(64), 0, stream>>>(ctl, hist, shifts[s]);
  }
  k_collect<<<dim3(1024), dim3(256), 0, stream>>>(keys, ctl, sel, tie);
  k_tiepick<<<dim3(1), dim3(256), 0, stream>>>(ctl, tie, sel);
  k_build<<<dim3(47), dim3(256), 0, stream>>>(keys, sel, comps);
  k_rank<<<dim3(47), dim3(256), 0, stream>>>(comps, sel, ordIdx);
  k_decode<<<dim3(47), dim3(256), 0, stream>>>(bbox, ordIdx, props, areas);
  k_mask<<<dim3(188, 188), dim3(64), 0, stream>>>(props, areas, mask);
  k_nms<<<dim3(1), dim3(64), 0, stream>>>(mask, keep);
  k_out<<<dim3(8), dim3(256), 0, stream>>>(keep, props, out);
}

// Round 2
// 1162.640 us; speedup vs baseline: 1.7627x; 1.7627x over previous
//
#include <hip/hip_runtime.h>
#include <cstdint>
#include <cstddef>

#pragma clang fp contract(off)

#define N_ANCH 2359296
#define K_PRE  12000
#define K_POST 2000
#define NWORD  188
#define TIE_CAP 65536

typedef unsigned int u32;
typedef unsigned long long u64;

__constant__ float c_anch[9][4] = {
  { -84.f,  -40.f,   99.f,   55.f },
  { -176.f, -88.f,  191.f,  103.f },
  { -360.f, -184.f, 375.f,  199.f },
  { -56.f,  -56.f,   71.f,   71.f },
  { -120.f, -120.f, 135.f,  135.f },
  { -248.f, -248.f, 263.f,  263.f },
  { -36.f,  -80.f,   51.f,   95.f },
  { -80.f,  -168.f,  95.f,  183.f },
  { -168.f, -344.f, 183.f,  359.f },
};

// Replica of XLA:CPU GenerateVF32Exp (Cephes/Eigen expf), UNFUSED mul/add.
__device__ __forceinline__ float pexpf(float xin) {
#pragma clang fp contract(off)
  const float exp_hi = 88.3762626647950f;
  const float exp_lo = -88.3762626647949f;
  const float LOG2EF = 1.44269504088896341f;
  const float C1 = 0.693359375f;
  const float C2 = -2.12194440e-4f;
  const float p0 = 1.9875691500E-4f;
  const float p1 = 1.3981999507E-3f;
  const float p2 = 8.3334519073E-3f;
  const float p3 = 4.1665795894E-2f;
  const float p4 = 1.6666665459E-1f;
  const float p5 = 5.0000001201E-1f;
  float x = fminf(fmaxf(xin, exp_lo), exp_hi);
  float fx = floorf(x * LOG2EF + 0.5f);
  float tmp = C1 * fx;
  float z = C2 * fx;
  x = x - tmp;
  x = x - z;
  z = x * x;
  float y = x * p0 + p1;
  y = y * x + p2;
  y = y * x + p3;
  y = y * x + p4;
  y = y * x + p5;
  y = y * z + x;
  y = 1.0f + y;
  int n = (int)fx;
  u32 e = ((u32)(n + 127)) << 23;
  return y * __uint_as_float(e);
}

__device__ __forceinline__ void decode_box(const float* __restrict__ bbox, int aidx,
                                           float4* ob, float* oarea, bool* okeep) {
#pragma clang fp contract(off)
  int pos = aidx / 9;
  int a = aidx - pos * 9;
  int w = pos & 511;
  int h = pos >> 9;
  float shx = (float)(w * 8);
  float shy = (float)(h * 8);
  float ax1 = c_anch[a][0] + shx;
  float ay1 = c_anch[a][1] + shy;
  float ax2 = c_anch[a][2] + shx;
  float ay2 = c_anch[a][3] + shy;
  float aw = (ax2 - ax1) + 1.0f;
  float ah = (ay2 - ay1) + 1.0f;
  float acx = ax1 + 0.5f * aw;
  float acy = ay1 + 0.5f * ah;
  const float* d = bbox + (size_t)pos * 36 + (size_t)a * 4;
  float dx = d[0], dy = d[1], dw = d[2], dh = d[3];
  float pcx = dx * aw + acx;
  float pcy = dy * ah + acy;
  float pw = pexpf(dw) * aw;
  float ph = pexpf(dh) * ah;
  float x1 = pcx - 0.5f * pw;
  float y1 = pcy - 0.5f * ph;
  float x2 = pcx + 0.5f * pw;
  float y2 = pcy + 0.5f * ph;
  x1 = fminf(fmaxf(x1, 0.0f), 4095.0f);
  y1 = fminf(fmaxf(y1, 0.0f), 4095.0f);
  x2 = fminf(fmaxf(x2, 0.0f), 4095.0f);
  y2 = fminf(fmaxf(y2, 0.0f), 4095.0f);
  *ob = make_float4(x1, y1, x2, y2);
  float ww = (x2 - x1) + 1.0f;
  float hh = (y2 - y1) + 1.0f;
  *oarea = ww * hh;
  *okeep = (ww >= 16.0f) && (hh >= 16.0f);
}

__global__ void k_scores(const float* __restrict__ cls, const float* __restrict__ bbox,
                         u32* __restrict__ keys) {
#pragma clang fp contract(off)
  int t = blockIdx.x * blockDim.x + threadIdx.x;
  if (t >= N_ANCH) return;
  int pos = t / 9;
  int a = t - pos * 9;
  float s0 = cls[(size_t)pos * 18 + a];
  float s1 = cls[(size_t)pos * 18 + 9 + a];
  float m = fmaxf(s0, s1);
  float e0 = pexpf(s0 - m);
  float e1 = pexpf(s1 - m);
  float p = e1 / (e0 + e1);
  float4 box; float area; bool km;
  decode_box(bbox, t, &box, &area, &km);
  keys[t] = km ? (__float_as_uint(p) | 0x80000000u) : 0u;
}

__global__ void k_ctl_init(u32* ctl, u32* hist) {
  int t = threadIdx.x;
  if (t < 16) ctl[t] = (t == 1) ? (u32)K_PRE : 0u;
  if (t < 256) hist[t] = 0u;
}

__global__ void k_hist(const u32* __restrict__ keys, const u32* __restrict__ ctl,
                       u32* __restrict__ hist, int shift) {
  __shared__ u32 lh[256];
  lh[threadIdx.x] = 0u;
  __syncthreads();
  u32 prefix = ctl[0];
  u32 msk = (shift == 24) ? 0u : (0xFFFFFFFFu << (shift + 8));
  int stride = gridDim.x * blockDim.x;
  for (int i = blockIdx.x * blockDim.x + threadIdx.x; i < N_ANCH; i += stride) {
    u32 k = keys[i];
    if ((k & msk) == prefix) atomicAdd(&lh[(k >> shift) & 0xFFu], 1u);
  }
  __syncthreads();
  if (lh[threadIdx.x]) atomicAdd(&hist[threadIdx.x], lh[threadIdx.x]);
}

// Parallel scan: pick d* = max{d : suffix(d) >= krem}; krem' = krem - suffix(d*+1)
__global__ void k_scan(u32* ctl, u32* hist, int shift) {
  __shared__ u32 sh[256];
  __shared__ u32 horig[256];
  __shared__ int s_d;
  int t = threadIdx.x;
  u32 h = hist[t];
  sh[t] = h; horig[t] = h;
  if (t == 0) s_d = 0;
  u32 krem = ctl[1];
  __syncthreads();
  u32 v = h;
  for (int off = 1; off < 256; off <<= 1) {
    u32 add = (t + off < 256) ? sh[t + off] : 0u;
    __syncthreads();
    v += add;
    sh[t] = v;
    __syncthreads();
  }
  if (sh[t] >= krem) atomicMax(&s_d, t);
  __syncthreads();
  if (t == 0) {
    int d = s_d;
    u32 cum = sh[d] - horig[d];
    ctl[0] |= ((u32)d) << shift;
    ctl[1] = krem - cum;
    if (shift == 0) { ctl[2] = ctl[0]; ctl[3] = ctl[1]; }
  }
  hist[t] = 0u;
}

__global__ void k_collect(const u32* __restrict__ keys, u32* __restrict__ ctl,
                          int* __restrict__ sel, int* __restrict__ tie) {
  u32 kstar = ctl[2];
  int stride = gridDim.x * blockDim.x;
  for (int i = blockIdx.x * blockDim.x + threadIdx.x; i < N_ANCH; i += stride) {
    u32 k = keys[i];
    if (k > kstar) {
      u32 p = atomicAdd(&ctl[4], 1u);
      sel[p] = i;
    } else if (k == kstar) {
      u32 p = atomicAdd(&ctl[5], 1u);
      if (p < TIE_CAP) tie[p] = i;
    }
  }
}

__global__ void k_tiepick(const u32* __restrict__ ctl, const int* __restrict__ tie,
                          int* __restrict__ sel) {
  u32 T = ctl[5]; if (T > TIE_CAP) T = TIE_CAP;
  if (T > 8192u) T = 8192u;
  u32 need = ctl[3];
  u32 base = ctl[4];
  for (u32 t = threadIdx.x; t < T; t += blockDim.x) {
    int v = tie[t];
    u32 r = 0;
    for (u32 u = 0; u < T; ++u) r += (tie[u] < v) ? 1u : 0u;
    if (r < need) sel[base + r] = v;
  }
}

__global__ void k_build(const u32* __restrict__ keys, const int* __restrict__ sel,
                        u64* __restrict__ comps) {
  int t = blockIdx.x * blockDim.x + threadIdx.x;
  if (t >= K_PRE) return;
  int idx = sel[t];
  u64 key = (u64)keys[idx];
  comps[t] = (key << 32) | (u64)(0xFFFFFFFFu - (u32)idx);
}

// O(K^2) rank sort fused with box decode: rank == lax.top_k position.
__global__ void k_rankdec(const u64* __restrict__ comps, const int* __restrict__ sel,
                          const float* __restrict__ bbox,
                          float4* __restrict__ props, float* __restrict__ areas) {
  int t = blockIdx.x * blockDim.x + threadIdx.x;
  if (t >= K_PRE) return;
  u64 c = comps[t];
  int cnt = 0;
#pragma unroll 8
  for (int j = 0; j < K_PRE; ++j) cnt += (comps[j] > c) ? 1 : 0;
  float4 box; float area; bool km;
  decode_box(bbox, sel[t], &box, &area, &km);
  props[cnt] = box;
  areas[cnt] = area;
}

__global__ void k_mask(const float4* __restrict__ props, const float* __restrict__ areas,
                       u64* __restrict__ mask) {
#pragma clang fp contract(off)
  __shared__ float4 bj[64];
  __shared__ float aj[64];
  int wj = blockIdx.y;
  int j0 = wj * 64;
  int jt = j0 + threadIdx.x;
  bj[threadIdx.x] = props[jt];
  aj[threadIdx.x] = areas[jt];
  __syncthreads();
  int i = blockIdx.x * 64 + threadIdx.x;
  float4 bi = props[i];
  float ai = areas[i];
  u64 bits = 0;
  for (int jj = 0; jj < 64; ++jj) {
    int j = j0 + jj;
    float4 bb = bj[jj];
    float xx1 = fmaxf(bi.x, bb.x);
    float yy1 = fmaxf(bi.y, bb.y);
    float xx2 = fminf(bi.z, bb.z);
    float yy2 = fminf(bi.w, bb.w);
    float w = fmaxf(0.0f, (xx2 - xx1) + 1.0f);
    float h = fmaxf(0.0f, (yy2 - yy1) + 1.0f);
    float inter = w * h;
    float iou = inter / ((ai + aj[jj]) - inter);
    if ((iou > 0.7f) && (j < K_PRE)) bits |= (1ull << jj);
  }
  mask[(size_t)i * NWORD + wj] = bits;
}

// Blocked greedy NMS. Key fact: keeps are strictly increasing in index, so
// suppression of j depends only on kept boxes with index < j. Per 64-chunk:
// wave 0 decides keeps serially via the diagonal block (shfl, no memory in the
// chain); waves 1-3 OR the kept rows into the LDS suppression bitset for all
// future words in parallel (OR is commutative). 188 serial chunk steps instead
// of 2000 serial HBM row fetches. Output gather fused at the end.
__global__ void __launch_bounds__(256) k_nms(const u64* __restrict__ mask,
                                             const float4* __restrict__ props,
                                             float* __restrict__ out) {
  __shared__ u64 rem[NWORD];
  __shared__ int kept[64];
  __shared__ int keepb[K_POST];
  __shared__ int s_nk, s_kk;
  int tid = threadIdx.x;
  int lane = tid & 63;
  int wave = tid >> 6;
  for (int w = tid; w < NWORD; w += 256) {
    int base = w * 64;
    u64 v;
    if (base + 64 <= K_PRE) v = 0ull;
    else if (base >= K_PRE) v = ~0ull;
    else v = (~0ull) << (K_PRE - base);
    rem[w] = v;
  }
  if (tid == 0) { s_nk = 0; s_kk = 0; }
  __syncthreads();
  u64 diag = 0;
  if (wave == 0) diag = mask[(size_t)lane * NWORD + 0];  // chunk 0 diagonal
  for (int c = 0; c < NWORD; ++c) {
    if (s_nk >= K_POST) break;
    if (wave == 0) {
      u64 w = ~rem[c];
      int kk = 0;
      int nk = s_nk;
      while (w && nk < K_POST) {
        int j = (int)__builtin_ctzll(w);
        if (lane == 0) { keepb[nk] = c * 64 + j; kept[kk] = c * 64 + j; }
        nk++; kk++;
        u64 dj = __shfl(diag, j);
        w &= ~dj;
        w &= ~(1ull << j);
      }
      if (lane == 0) { s_nk = nk; s_kk = kk; }
    }
    __syncthreads();
    int kk = s_kk;
    if (wave == 0) {
      if (c + 1 < NWORD)  // prefetch next diagonal while others bulk-OR
        diag = mask[(size_t)((c + 1) * 64 + lane) * NWORD + (c + 1)];
    } else {
      int w = c + 1 + (tid - 64);
      if (w < NWORD && kk > 0) {
        u64 v = rem[w];
        for (int q = 0; q < kk; ++q) v |= mask[(size_t)kept[q] * NWORD + w];
        rem[w] = v;
      }
    }
    __syncthreads();
  }
  int nk = s_nk;
  for (int t = tid; t < K_POST; t += 256) {
    int kidx = (t < nk) ? keepb[t] : 0;  // exhausted: argmax over -inf -> 0
    float4 b = props[kidx];
    out[t * 5 + 0] = 0.0f;
    out[t * 5 + 1] = b.x;
    out[t * 5 + 2] = b.y;
    out[t * 5 + 3] = b.z;
    out[t * 5 + 4] = b.w;
  }
}

extern "C" void kernel_launch(void* const* d_in, const int* in_sizes, int n_in,
                              void* d_out, int out_size, void* d_ws, size_t ws_size,
                              hipStream_t stream) {
  const float* cls  = (const float*)d_in[0];
  const float* bbox = (const float*)d_in[1];
  float* out = (float*)d_out;
  char* ws = (char*)d_ws;

  // Layout (mask overlays keys/ctl/hist/sel/tie, all dead before k_mask):
  u64* mask    = (u64*)ws;                    // [0, 18096128) u64[12032*188]
  u32* keys    = (u32*)ws;                    // [0, 9437184)
  u32* ctl     = (u32*)(ws + 9437184);
  u32* hist    = (u32*)(ws + 9437248);
  int* sel     = (int*)(ws + 9438464);
  int* tie     = (int*)(ws + 9486592);
  u64* comps   = (u64*)(ws + 18096128);
  float4* props= (float4*)(ws + 18240512);
  float* areas = (float*)(ws + 18433024);

  k_scores<<<dim3((N_ANCH + 255) / 256), dim3(256), 0, stream>>>(cls, bbox, keys);
  k_ctl_init<<<dim3(1), dim3(256), 0, stream>>>(ctl, hist);
  const int shifts[4] = {24, 16, 8, 0};
  for (int s = 0; s < 4; ++s) {
    k_hist<<<dim3(1024), dim3(256), 0, stream>>>(keys, ctl, hist, shifts[s]);
    k_scan<<<dim3(1), dim3(256), 0, stream>>>(ctl, hist, shifts[s]);
  }
  k_collect<<<dim3(1024), dim3(256), 0, stream>>>(keys, ctl, sel, tie);
  k_tiepick<<<dim3(1), dim3(256), 0, stream>>>(ctl, tie, sel);
  k_build<<<dim3(47), dim3(256), 0, stream>>>(keys, sel, comps);
  k_rankdec<<<dim3(47), dim3(256), 0, stream>>>(comps, sel, bbox, props, areas);
  k_mask<<<dim3(188, 188), dim3(64), 0, stream>>>(props, areas, mask);
  k_nms<<<dim3(1), dim3(256), 0, stream>>>(mask, props, out);
}

// Round 3
// 638.690 us; speedup vs baseline: 3.2087x; 1.8204x over previous
//
#include <hip/hip_runtime.h>
#include <cstdint>
#include <cstddef>

#pragma clang fp contract(off)

#define N_ANCH 2359296
#define K_PRE  12000
#define K_POST 2000
#define NWORD  188
#define TIE_CAP 65536

typedef unsigned int u32;
typedef unsigned long long u64;

__constant__ float c_anch[9][4] = {
  { -84.f,  -40.f,   99.f,   55.f },
  { -176.f, -88.f,  191.f,  103.f },
  { -360.f, -184.f, 375.f,  199.f },
  { -56.f,  -56.f,   71.f,   71.f },
  { -120.f, -120.f, 135.f,  135.f },
  { -248.f, -248.f, 263.f,  263.f },
  { -36.f,  -80.f,   51.f,   95.f },
  { -80.f,  -168.f,  95.f,  183.f },
  { -168.f, -344.f, 183.f,  359.f },
};

// Replica of XLA:CPU GenerateVF32Exp (Cephes/Eigen expf), UNFUSED mul/add.
__device__ __forceinline__ float pexpf(float xin) {
#pragma clang fp contract(off)
  const float exp_hi = 88.3762626647950f;
  const float exp_lo = -88.3762626647949f;
  const float LOG2EF = 1.44269504088896341f;
  const float C1 = 0.693359375f;
  const float C2 = -2.12194440e-4f;
  const float p0 = 1.9875691500E-4f;
  const float p1 = 1.3981999507E-3f;
  const float p2 = 8.3334519073E-3f;
  const float p3 = 4.1665795894E-2f;
  const float p4 = 1.6666665459E-1f;
  const float p5 = 5.0000001201E-1f;
  float x = fminf(fmaxf(xin, exp_lo), exp_hi);
  float fx = floorf(x * LOG2EF + 0.5f);
  float tmp = C1 * fx;
  float z = C2 * fx;
  x = x - tmp;
  x = x - z;
  z = x * x;
  float y = x * p0 + p1;
  y = y * x + p2;
  y = y * x + p3;
  y = y * x + p4;
  y = y * x + p5;
  y = y * z + x;
  y = 1.0f + y;
  int n = (int)fx;
  u32 e = ((u32)(n + 127)) << 23;
  return y * __uint_as_float(e);
}

__device__ __forceinline__ void decode_box(const float* __restrict__ bbox, int aidx,
                                           float4* ob, float* oarea, bool* okeep) {
#pragma clang fp contract(off)
  int pos = aidx / 9;
  int a = aidx - pos * 9;
  int w = pos & 511;
  int h = pos >> 9;
  float shx = (float)(w * 8);
  float shy = (float)(h * 8);
  float ax1 = c_anch[a][0] + shx;
  float ay1 = c_anch[a][1] + shy;
  float ax2 = c_anch[a][2] + shx;
  float ay2 = c_anch[a][3] + shy;
  float aw = (ax2 - ax1) + 1.0f;
  float ah = (ay2 - ay1) + 1.0f;
  float acx = ax1 + 0.5f * aw;
  float acy = ay1 + 0.5f * ah;
  const float* d = bbox + (size_t)pos * 36 + (size_t)a * 4;
  float dx = d[0], dy = d[1], dw = d[2], dh = d[3];
  float pcx = dx * aw + acx;
  float pcy = dy * ah + acy;
  float pw = pexpf(dw) * aw;
  float ph = pexpf(dh) * ah;
  float x1 = pcx - 0.5f * pw;
  float y1 = pcy - 0.5f * ph;
  float x2 = pcx + 0.5f * pw;
  float y2 = pcy + 0.5f * ph;
  x1 = fminf(fmaxf(x1, 0.0f), 4095.0f);
  y1 = fminf(fmaxf(y1, 0.0f), 4095.0f);
  x2 = fminf(fmaxf(x2, 0.0f), 4095.0f);
  y2 = fminf(fmaxf(y2, 0.0f), 4095.0f);
  *ob = make_float4(x1, y1, x2, y2);
  float ww = (x2 - x1) + 1.0f;
  float hh = (y2 - y1) + 1.0f;
  *oarea = ww * hh;
  *okeep = (ww >= 16.0f) && (hh >= 16.0f);
}

__global__ void k_scores(const float* __restrict__ cls, const float* __restrict__ bbox,
                         u32* __restrict__ keys) {
#pragma clang fp contract(off)
  int t = blockIdx.x * blockDim.x + threadIdx.x;
  if (t >= N_ANCH) return;
  int pos = t / 9;
  int a = t - pos * 9;
  float s0 = cls[(size_t)pos * 18 + a];
  float s1 = cls[(size_t)pos * 18 + 9 + a];
  float m = fmaxf(s0, s1);
  float e0 = pexpf(s0 - m);
  float e1 = pexpf(s1 - m);
  float p = e1 / (e0 + e1);
  float4 box; float area; bool km;
  decode_box(bbox, t, &box, &area, &km);
  keys[t] = km ? (__float_as_uint(p) | 0x80000000u) : 0u;
}

__global__ void k_ctl_init(u32* ctl, u32* hist) {
  int t = threadIdx.x;
  if (t < 16) ctl[t] = (t == 1) ? (u32)K_PRE : 0u;
  if (t < 256) hist[t] = 0u;
}

__global__ void k_hist(const u32* __restrict__ keys, const u32* __restrict__ ctl,
                       u32* __restrict__ hist, int shift) {
  __shared__ u32 lh[256];
  lh[threadIdx.x] = 0u;
  __syncthreads();
  u32 prefix = ctl[0];
  u32 msk = (shift == 24) ? 0u : (0xFFFFFFFFu << (shift + 8));
  int stride = gridDim.x * blockDim.x;
  for (int i = blockIdx.x * blockDim.x + threadIdx.x; i < N_ANCH; i += stride) {
    u32 k = keys[i];
    if ((k & msk) == prefix) atomicAdd(&lh[(k >> shift) & 0xFFu], 1u);
  }
  __syncthreads();
  if (lh[threadIdx.x]) atomicAdd(&hist[threadIdx.x], lh[threadIdx.x]);
}

__global__ void k_scan(u32* ctl, u32* hist, int shift) {
  __shared__ u32 sh[256];
  __shared__ u32 horig[256];
  __shared__ int s_d;
  int t = threadIdx.x;
  u32 h = hist[t];
  sh[t] = h; horig[t] = h;
  if (t == 0) s_d = 0;
  u32 krem = ctl[1];
  __syncthreads();
  u32 v = h;
  for (int off = 1; off < 256; off <<= 1) {
    u32 add = (t + off < 256) ? sh[t + off] : 0u;
    __syncthreads();
    v += add;
    sh[t] = v;
    __syncthreads();
  }
  if (sh[t] >= krem) atomicMax(&s_d, t);
  __syncthreads();
  if (t == 0) {
    int d = s_d;
    u32 cum = sh[d] - horig[d];
    ctl[0] |= ((u32)d) << shift;
    ctl[1] = krem - cum;
    if (shift == 0) { ctl[2] = ctl[0]; ctl[3] = ctl[1]; }
  }
  hist[t] = 0u;
}

__global__ void k_collect(const u32* __restrict__ keys, u32* __restrict__ ctl,
                          int* __restrict__ sel, int* __restrict__ tie) {
  u32 kstar = ctl[2];
  int stride = gridDim.x * blockDim.x;
  for (int i = blockIdx.x * blockDim.x + threadIdx.x; i < N_ANCH; i += stride) {
    u32 k = keys[i];
    if (k > kstar) {
      u32 p = atomicAdd(&ctl[4], 1u);
      sel[p] = i;
    } else if (k == kstar) {
      u32 p = atomicAdd(&ctl[5], 1u);
      if (p < TIE_CAP) tie[p] = i;
    }
  }
}

__global__ void k_tiepick(const u32* __restrict__ ctl, const int* __restrict__ tie,
                          int* __restrict__ sel) {
  u32 T = ctl[5]; if (T > TIE_CAP) T = TIE_CAP;
  if (T > 8192u) T = 8192u;
  u32 need = ctl[3];
  u32 base = ctl[4];
  for (u32 t = threadIdx.x; t < T; t += blockDim.x) {
    int v = tie[t];
    u32 r = 0;
    for (u32 u = 0; u < T; ++u) r += (tie[u] < v) ? 1u : 0u;
    if (r < need) sel[base + r] = v;
  }
}

__global__ void k_build(const u32* __restrict__ keys, const int* __restrict__ sel,
                        u64* __restrict__ comps) {
  int t = blockIdx.x * blockDim.x + threadIdx.x;
  if (t >= K_PRE) return;
  int idx = sel[t];
  u64 key = (u64)keys[idx];
  comps[t] = (key << 32) | (u64)(0xFFFFFFFFu - (u32)idx);
}

// Rank sort v2: one wave per 8 candidates; lanes stride the j-scan (coalesced,
// L2-resident), butterfly-reduce 8 counters, 8 lanes decode+scatter.
// 12000 = 375 blocks * 4 waves * 8.
__global__ void k_rankdec(const u64* __restrict__ comps, const int* __restrict__ sel,
                          const float* __restrict__ bbox,
                          float4* __restrict__ props, float* __restrict__ areas) {
  int lane = threadIdx.x & 63;
  int wave = threadIdx.x >> 6;
  int base = (blockIdx.x * 4 + wave) * 8;
  u64 c0 = comps[base + 0], c1 = comps[base + 1], c2 = comps[base + 2], c3 = comps[base + 3];
  u64 c4 = comps[base + 4], c5 = comps[base + 5], c6 = comps[base + 6], c7 = comps[base + 7];
  int n0 = 0, n1 = 0, n2 = 0, n3 = 0, n4 = 0, n5 = 0, n6 = 0, n7 = 0;
#pragma unroll 4
  for (int j = lane; j < K_PRE; j += 64) {
    u64 v = comps[j];
    n0 += (v > c0); n1 += (v > c1); n2 += (v > c2); n3 += (v > c3);
    n4 += (v > c4); n5 += (v > c5); n6 += (v > c6); n7 += (v > c7);
  }
  for (int off = 32; off; off >>= 1) {
    n0 += __shfl_xor(n0, off); n1 += __shfl_xor(n1, off);
    n2 += __shfl_xor(n2, off); n3 += __shfl_xor(n3, off);
    n4 += __shfl_xor(n4, off); n5 += __shfl_xor(n5, off);
    n6 += __shfl_xor(n6, off); n7 += __shfl_xor(n7, off);
  }
  int rk = n0;
  rk = (lane == 1) ? n1 : rk; rk = (lane == 2) ? n2 : rk;
  rk = (lane == 3) ? n3 : rk; rk = (lane == 4) ? n4 : rk;
  rk = (lane == 5) ? n5 : rk; rk = (lane == 6) ? n6 : rk;
  rk = (lane == 7) ? n7 : rk;
  if (lane < 8) {
    float4 box; float area; bool km;
    decode_box(bbox, sel[base + lane], &box, &area, &km);
    props[rk] = box;
    areas[rk] = area;
  }
}

// IoU bitmask, upper triangle only (k_nms reads only words w >= row_chunk).
__global__ void k_mask(const float4* __restrict__ props, const float* __restrict__ areas,
                       u64* __restrict__ mask) {
#pragma clang fp contract(off)
  if (blockIdx.y < blockIdx.x) return;
  __shared__ float4 bj[64];
  __shared__ float aj[64];
  int wj = blockIdx.y;
  int j0 = wj * 64;
  bj[threadIdx.x] = props[j0 + threadIdx.x];
  aj[threadIdx.x] = areas[j0 + threadIdx.x];
  __syncthreads();
  int i = blockIdx.x * 64 + threadIdx.x;
  float4 bi = props[i];
  float ai = areas[i];
  u64 bits = 0;
  for (int jj = 0; jj < 64; ++jj) {
    int j = j0 + jj;
    float4 bb = bj[jj];
    float xx1 = fmaxf(bi.x, bb.x);
    float yy1 = fmaxf(bi.y, bb.y);
    float xx2 = fminf(bi.z, bb.z);
    float yy2 = fminf(bi.w, bb.w);
    float w = fmaxf(0.0f, (xx2 - xx1) + 1.0f);
    float h = fmaxf(0.0f, (yy2 - yy1) + 1.0f);
    float inter = w * h;
    float iou = inter / ((ai + aj[jj]) - inter);
    if ((iou > 0.7f) && (j < K_PRE)) bits |= (1ull << jj);
  }
  mask[(size_t)i * NWORD + wj] = bits;
}

// Blocked greedy NMS v3: no HBM load on the serial chain.
//  - diag for chunk c+1: loaded by wave0 at chunk-c start, used next chunk.
//  - word c+1 of chunk-c rows: loaded by wave1 one chunk EARLY (spec), combined
//    at chunk-c end with a shfl-OR over the kept mask (LDS/reg only).
//  - words >= c+1 for chunk c-1 keeps: lazy, one word per thread (NWORD-c <= 192),
//    fixed-8 idempotent-padded load batch issued in P0, consumed in P2.
__global__ void __launch_bounds__(256) k_nms(const u64* __restrict__ mask,
                                             const float4* __restrict__ props,
                                             float* __restrict__ out) {
  __shared__ u64 rem[NWORD];
  __shared__ int keepb[K_POST];
  __shared__ int kept[2][64];
  __shared__ int s_kk[2];
  __shared__ u64 s_km[2];
  __shared__ int s_nk;
  int tid = threadIdx.x;
  int lane = tid & 63;
  int wave = tid >> 6;
  for (int w = tid; w < NWORD; w += 256) {
    int base = w * 64;
    u64 v;
    if (base + 64 <= K_PRE) v = 0ull;
    else if (base >= K_PRE) v = ~0ull;
    else v = (~0ull) << (K_PRE - base);
    rem[w] = v;
  }
  if (tid == 0) { s_nk = 0; s_kk[0] = 0; s_kk[1] = 0; s_km[0] = 0; s_km[1] = 0; }
  __syncthreads();
  u64 diagA = 0, diagB = 0, specA = 0, specB = 0;
  if (wave == 0) diagA = mask[(size_t)lane * NWORD + 0];       // chunk 0 diag
  if (wave == 1) specA = mask[(size_t)lane * NWORD + 1];       // chunk 0 rows, word 1
  int nk_reg = 0;  // wave0 lane-shared running keep count

  for (int c = 0; c < NWORD; ++c) {
    if (s_nk >= K_POST) break;
    int par = c & 1;
    int pprev = par ^ 1;
    int kkp = s_kk[pprev];
    // ---- P0: issue loads + decision ----
    u64 lz0 = 0, lz1 = 0, lz2 = 0, lz3 = 0, lz4 = 0, lz5 = 0, lz6 = 0, lz7 = 0;
    int lw = c + 1 + (tid - 64);
    if (wave >= 1 && kkp > 0 && lw < NWORD) {
      int m = kkp - 1;
      const u64* mp = mask;
      lz0 = mp[(size_t)kept[pprev][0] * NWORD + lw];
      lz1 = mp[(size_t)kept[pprev][min(1, m)] * NWORD + lw];
      lz2 = mp[(size_t)kept[pprev][min(2, m)] * NWORD + lw];
      lz3 = mp[(size_t)kept[pprev][min(3, m)] * NWORD + lw];
      lz4 = mp[(size_t)kept[pprev][min(4, m)] * NWORD + lw];
      lz5 = mp[(size_t)kept[pprev][min(5, m)] * NWORD + lw];
      lz6 = mp[(size_t)kept[pprev][min(6, m)] * NWORD + lw];
      lz7 = mp[(size_t)kept[pprev][min(7, m)] * NWORD + lw];
    }
    if (wave == 0 && c + 1 < NWORD)
      diagB = mask[(size_t)(((c + 1) << 6) | lane) * NWORD + (c + 1)];
    if (wave == 1 && c + 2 < NWORD)
      specB = mask[(size_t)(((c + 1) << 6) | lane) * NWORD + (c + 2)];
    if (wave == 0) {
      u64 w = ~rem[c];
      int nk = s_nk;
      int kk = 0;
      u64 km = 0;
      while (w && nk < K_POST) {
        int j = (int)__builtin_ctzll(w);
        u64 dj = __shfl(diagA, j);
        if (lane == 0) { keepb[nk] = (c << 6) | j; kept[par][kk] = (c << 6) | j; }
        km |= (1ull << j);
        nk++; kk++;
        w &= ~dj;
        w &= ~(1ull << j);
      }
      if (lane == 0) { s_kk[par] = kk; s_km[par] = km; }
      nk_reg = nk;
    }
    __syncthreads();   // barrier1
    // ---- P2: consume ----
    u64 kmc = s_km[par];
    if (wave == 1 && c + 1 < NWORD) {
      u64 v = ((kmc >> lane) & 1ull) ? specA : 0ull;
      for (int off = 32; off; off >>= 1) v |= __shfl_xor(v, off);
      if (lane == 0) atomicOr(&rem[c + 1], v);
      specA = specB;
    }
    if (wave >= 1 && kkp > 0 && lw < NWORD) {
      u64 v = lz0 | lz1 | lz2 | lz3 | lz4 | lz5 | lz6 | lz7;
      for (int q0 = 8; q0 < kkp; q0 += 8) {
        int m = kkp - 1;
#pragma unroll
        for (int q = 0; q < 8; ++q)
          v |= mask[(size_t)kept[pprev][min(q0 + q, m)] * NWORD + lw];
      }
      atomicOr(&rem[lw], v);
    }
    if (wave == 0) diagA = diagB;
    if (tid == 0) s_nk = nk_reg;
    __syncthreads();   // barrier2
  }
  int nk = s_nk;
  for (int t = tid; t < K_POST; t += 256) {
    int kidx = (t < nk) ? keepb[t] : 0;  // exhausted: argmax over -inf -> 0
    float4 b = props[kidx];
    out[t * 5 + 0] = 0.0f;
    out[t * 5 + 1] = b.x;
    out[t * 5 + 2] = b.y;
    out[t * 5 + 3] = b.z;
    out[t * 5 + 4] = b.w;
  }
}

extern "C" void kernel_launch(void* const* d_in, const int* in_sizes, int n_in,
                              void* d_out, int out_size, void* d_ws, size_t ws_size,
                              hipStream_t stream) {
  const float* cls  = (const float*)d_in[0];
  const float* bbox = (const float*)d_in[1];
  float* out = (float*)d_out;
  char* ws = (char*)d_ws;

  u64* mask    = (u64*)ws;                    // [0, 18096128) u64[12032*188]
  u32* keys    = (u32*)ws;                    // [0, 9437184) overlays mask (dead before k_mask)
  u32* ctl     = (u32*)(ws + 9437184);
  u32* hist    = (u32*)(ws + 9437248);
  int* sel     = (int*)(ws + 9438464);
  int* tie     = (int*)(ws + 9486592);
  u64* comps   = (u64*)(ws + 18096128);
  float4* props= (float4*)(ws + 18240512);
  float* areas = (float*)(ws + 18433024);

  k_scores<<<dim3((N_ANCH + 255) / 256), dim3(256), 0, stream>>>(cls, bbox, keys);
  k_ctl_init<<<dim3(1), dim3(256), 0, stream>>>(ctl, hist);
  const int shifts[4] = {24, 16, 8, 0};
  for (int s = 0; s < 4; ++s) {
    k_hist<<<dim3(1024), dim3(256), 0, stream>>>(keys, ctl, hist, shifts[s]);
    k_scan<<<dim3(1), dim3(256), 0, stream>>>(ctl, hist, shifts[s]);
  }
  k_collect<<<dim3(1024), dim3(256), 0, stream>>>(keys, ctl, sel, tie);
  k_tiepick<<<dim3(1), dim3(256), 0, stream>>>(ctl, tie, sel);
  k_build<<<dim3(47), dim3(256), 0, stream>>>(keys, sel, comps);
  k_rankdec<<<dim3(375), dim3(256), 0, stream>>>(comps, sel, bbox, props, areas);
  k_mask<<<dim3(188, 188), dim3(64), 0, stream>>>(props, areas, mask);
  k_nms<<<dim3(1), dim3(256), 0, stream>>>(mask, props, out);
}

// Round 4
// 631.014 us; speedup vs baseline: 3.2478x; 1.0122x over previous
//
#include <hip/hip_runtime.h>
#include <cstdint>
#include <cstddef>

#pragma clang fp contract(off)

#define N_ANCH 2359296
#define K_PRE  12000
#define K_POST 2000
#define NWORD  188
#define TIE_CAP 65536

typedef unsigned int u32;
typedef unsigned long long u64;

__constant__ float c_anch[9][4] = {
  { -84.f,  -40.f,   99.f,   55.f },
  { -176.f, -88.f,  191.f,  103.f },
  { -360.f, -184.f, 375.f,  199.f },
  { -56.f,  -56.f,   71.f,   71.f },
  { -120.f, -120.f, 135.f,  135.f },
  { -248.f, -248.f, 263.f,  263.f },
  { -36.f,  -80.f,   51.f,   95.f },
  { -80.f,  -168.f,  95.f,  183.f },
  { -168.f, -344.f, 183.f,  359.f },
};

// Replica of XLA:CPU GenerateVF32Exp (Cephes/Eigen expf), UNFUSED mul/add.
__device__ __forceinline__ float pexpf(float xin) {
#pragma clang fp contract(off)
  const float exp_hi = 88.3762626647950f;
  const float exp_lo = -88.3762626647949f;
  const float LOG2EF = 1.44269504088896341f;
  const float C1 = 0.693359375f;
  const float C2 = -2.12194440e-4f;
  const float p0 = 1.9875691500E-4f;
  const float p1 = 1.3981999507E-3f;
  const float p2 = 8.3334519073E-3f;
  const float p3 = 4.1665795894E-2f;
  const float p4 = 1.6666665459E-1f;
  const float p5 = 5.0000001201E-1f;
  float x = fminf(fmaxf(xin, exp_lo), exp_hi);
  float fx = floorf(x * LOG2EF + 0.5f);
  float tmp = C1 * fx;
  float z = C2 * fx;
  x = x - tmp;
  x = x - z;
  z = x * x;
  float y = x * p0 + p1;
  y = y * x + p2;
  y = y * x + p3;
  y = y * x + p4;
  y = y * x + p5;
  y = y * z + x;
  y = 1.0f + y;
  int n = (int)fx;
  u32 e = ((u32)(n + 127)) << 23;
  return y * __uint_as_float(e);
}

__device__ __forceinline__ void decode_box(const float* __restrict__ bbox, int aidx,
                                           float4* ob, float* oarea, bool* okeep) {
#pragma clang fp contract(off)
  int pos = aidx / 9;
  int a = aidx - pos * 9;
  int w = pos & 511;
  int h = pos >> 9;
  float shx = (float)(w * 8);
  float shy = (float)(h * 8);
  float ax1 = c_anch[a][0] + shx;
  float ay1 = c_anch[a][1] + shy;
  float ax2 = c_anch[a][2] + shx;
  float ay2 = c_anch[a][3] + shy;
  float aw = (ax2 - ax1) + 1.0f;
  float ah = (ay2 - ay1) + 1.0f;
  float acx = ax1 + 0.5f * aw;
  float acy = ay1 + 0.5f * ah;
  const float* d = bbox + (size_t)pos * 36 + (size_t)a * 4;
  float dx = d[0], dy = d[1], dw = d[2], dh = d[3];
  float pcx = dx * aw + acx;
  float pcy = dy * ah + acy;
  float pw = pexpf(dw) * aw;
  float ph = pexpf(dh) * ah;
  float x1 = pcx - 0.5f * pw;
  float y1 = pcy - 0.5f * ph;
  float x2 = pcx + 0.5f * pw;
  float y2 = pcy + 0.5f * ph;
  x1 = fminf(fmaxf(x1, 0.0f), 4095.0f);
  y1 = fminf(fmaxf(y1, 0.0f), 4095.0f);
  x2 = fminf(fmaxf(x2, 0.0f), 4095.0f);
  y2 = fminf(fmaxf(y2, 0.0f), 4095.0f);
  *ob = make_float4(x1, y1, x2, y2);
  float ww = (x2 - x1) + 1.0f;
  float hh = (y2 - y1) + 1.0f;
  *oarea = ww * hh;
  *okeep = (ww >= 16.0f) && (hh >= 16.0f);
}

__global__ void k_scores(const float* __restrict__ cls, const float* __restrict__ bbox,
                         u32* __restrict__ keys) {
#pragma clang fp contract(off)
  int t = blockIdx.x * blockDim.x + threadIdx.x;
  if (t >= N_ANCH) return;
  int pos = t / 9;
  int a = t - pos * 9;
  float s0 = cls[(size_t)pos * 18 + a];
  float s1 = cls[(size_t)pos * 18 + 9 + a];
  float m = fmaxf(s0, s1);
  float e0 = pexpf(s0 - m);
  float e1 = pexpf(s1 - m);
  float p = e1 / (e0 + e1);
  float4 box; float area; bool km;
  decode_box(bbox, t, &box, &area, &km);
  keys[t] = km ? (__float_as_uint(p) | 0x80000000u) : 0u;
}

__global__ void k_ctl_init(u32* ctl, u32* hist) {
  int t = threadIdx.x;
  if (t < 16) ctl[t] = (t == 1) ? (u32)K_PRE : 0u;
  if (t < 256) hist[t] = 0u;
}

// Histogram pass + fused last-block scan (device-scope last-block pattern).
__global__ void k_histscan(const u32* __restrict__ keys, u32* __restrict__ ctl,
                           u32* __restrict__ hist, int shift, int pass) {
  __shared__ u32 lh[256];
  __shared__ u32 s_last;
  int t = threadIdx.x;
  lh[t] = 0u;
  __syncthreads();
  u32 prefix = ctl[0];
  u32 msk = (shift == 24) ? 0u : (0xFFFFFFFFu << (shift + 8));
  int stride = gridDim.x * blockDim.x;
  for (int i = blockIdx.x * blockDim.x + t; i < N_ANCH; i += stride) {
    u32 k = keys[i];
    if ((k & msk) == prefix) atomicAdd(&lh[(k >> shift) & 0xFFu], 1u);
  }
  __syncthreads();
  if (lh[t]) atomicAdd(&hist[t], lh[t]);
  __syncthreads();
  if (t == 0) {
    __threadfence();
    u32 old = atomicAdd(&ctl[8 + pass], 1u);
    s_last = (old == gridDim.x - 1) ? 1u : 0u;
  }
  __syncthreads();
  if (!s_last) return;
  __threadfence();
  // scan: pick d* = max{d : suffix(d) >= krem}
  __shared__ u32 sh[256];
  __shared__ u32 horig[256];
  __shared__ int s_d;
  u32 h = atomicAdd(&hist[t], 0u);   // coherent read (bypass stale L1)
  sh[t] = h; horig[t] = h;
  if (t == 0) s_d = 0;
  u32 krem = ctl[1];
  __syncthreads();
  u32 v = h;
  for (int off = 1; off < 256; off <<= 1) {
    u32 add = (t + off < 256) ? sh[t + off] : 0u;
    __syncthreads();
    v += add;
    sh[t] = v;
    __syncthreads();
  }
  if (sh[t] >= krem) atomicMax(&s_d, t);
  __syncthreads();
  if (t == 0) {
    int d = s_d;
    u32 cum = sh[d] - horig[d];
    ctl[0] |= ((u32)d) << shift;
    ctl[1] = krem - cum;
    if (shift == 0) { ctl[2] = ctl[0]; ctl[3] = ctl[1]; }
  }
  hist[t] = 0u;
}

__global__ void k_collect(const u32* __restrict__ keys, u32* __restrict__ ctl,
                          int* __restrict__ sel, int* __restrict__ tie) {
  u32 kstar = ctl[2];
  int stride = gridDim.x * blockDim.x;
  for (int i = blockIdx.x * blockDim.x + threadIdx.x; i < N_ANCH; i += stride) {
    u32 k = keys[i];
    if (k > kstar) {
      u32 p = atomicAdd(&ctl[4], 1u);
      sel[p] = i;
    } else if (k == kstar) {
      u32 p = atomicAdd(&ctl[5], 1u);
      if (p < TIE_CAP) tie[p] = i;
    }
  }
}

__global__ void k_tiepick(const u32* __restrict__ ctl, const int* __restrict__ tie,
                          int* __restrict__ sel) {
  u32 T = ctl[5]; if (T > TIE_CAP) T = TIE_CAP;
  if (T > 8192u) T = 8192u;
  u32 need = ctl[3];
  u32 base = ctl[4];
  for (u32 t = threadIdx.x; t < T; t += blockDim.x) {
    int v = tie[t];
    u32 r = 0;
    for (u32 u = 0; u < T; ++u) r += (tie[u] < v) ? 1u : 0u;
    if (r < need) sel[base + r] = v;
  }
}

__global__ void k_build(const u32* __restrict__ keys, const int* __restrict__ sel,
                        u64* __restrict__ comps) {
  int t = blockIdx.x * blockDim.x + threadIdx.x;
  if (t >= K_PRE) return;
  int idx = sel[t];
  u64 key = (u64)keys[idx];
  comps[t] = (key << 32) | (u64)(0xFFFFFFFFu - (u32)idx);
}

// Rank sort: one wave per 8 candidates; lanes stride the j-scan (coalesced,
// L2-resident), butterfly-reduce, 8 lanes decode+scatter.
__global__ void k_rankdec(const u64* __restrict__ comps, const int* __restrict__ sel,
                          const float* __restrict__ bbox,
                          float4* __restrict__ props, float* __restrict__ areas) {
  int lane = threadIdx.x & 63;
  int wave = threadIdx.x >> 6;
  int base = (blockIdx.x * 4 + wave) * 8;
  u64 c0 = comps[base + 0], c1 = comps[base + 1], c2 = comps[base + 2], c3 = comps[base + 3];
  u64 c4 = comps[base + 4], c5 = comps[base + 5], c6 = comps[base + 6], c7 = comps[base + 7];
  int n0 = 0, n1 = 0, n2 = 0, n3 = 0, n4 = 0, n5 = 0, n6 = 0, n7 = 0;
#pragma unroll 4
  for (int j = lane; j < K_PRE; j += 64) {
    u64 v = comps[j];
    n0 += (v > c0); n1 += (v > c1); n2 += (v > c2); n3 += (v > c3);
    n4 += (v > c4); n5 += (v > c5); n6 += (v > c6); n7 += (v > c7);
  }
  for (int off = 32; off; off >>= 1) {
    n0 += __shfl_xor(n0, off); n1 += __shfl_xor(n1, off);
    n2 += __shfl_xor(n2, off); n3 += __shfl_xor(n3, off);
    n4 += __shfl_xor(n4, off); n5 += __shfl_xor(n5, off);
    n6 += __shfl_xor(n6, off); n7 += __shfl_xor(n7, off);
  }
  int rk = n0;
  rk = (lane == 1) ? n1 : rk; rk = (lane == 2) ? n2 : rk;
  rk = (lane == 3) ? n3 : rk; rk = (lane == 4) ? n4 : rk;
  rk = (lane == 5) ? n5 : rk; rk = (lane == 6) ? n6 : rk;
  rk = (lane == 7) ? n7 : rk;
  if (lane < 8) {
    float4 box; float area; bool km;
    decode_box(bbox, sel[base + lane], &box, &area, &km);
    props[rk] = box;
    areas[rk] = area;
  }
}

// IoU bitmask, upper triangle only (k_nms reads only words w >= row_chunk).
__global__ void k_mask(const float4* __restrict__ props, const float* __restrict__ areas,
                       u64* __restrict__ mask) {
#pragma clang fp contract(off)
  if (blockIdx.y < blockIdx.x) return;
  __shared__ float4 bj[64];
  __shared__ float aj[64];
  int wj = blockIdx.y;
  int j0 = wj * 64;
  bj[threadIdx.x] = props[j0 + threadIdx.x];
  aj[threadIdx.x] = areas[j0 + threadIdx.x];
  __syncthreads();
  int i = blockIdx.x * 64 + threadIdx.x;
  float4 bi = props[i];
  float ai = areas[i];
  u64 bits = 0;
  for (int jj = 0; jj < 64; ++jj) {
    int j = j0 + jj;
    float4 bb = bj[jj];
    float xx1 = fmaxf(bi.x, bb.x);
    float yy1 = fmaxf(bi.y, bb.y);
    float xx2 = fminf(bi.z, bb.z);
    float yy2 = fminf(bi.w, bb.w);
    float w = fmaxf(0.0f, (xx2 - xx1) + 1.0f);
    float h = fmaxf(0.0f, (yy2 - yy1) + 1.0f);
    float inter = w * h;
    float iou = inter / ((ai + aj[jj]) - inter);
    if ((iou > 0.7f) && (j < K_PRE)) bits |= (1ull << jj);
  }
  mask[(size_t)i * NWORD + wj] = bits;
}

// Far-path prefetch helpers (static register indexing only).
__device__ __forceinline__ void far_issue(const u64* __restrict__ mask,
                                          const int* __restrict__ kb, int kk, int lw,
                                          u64 (&lz)[32]) {
  int m = kk - 1;
#pragma unroll
  for (int g = 0; g < 4; ++g) {
    if (kk > g * 8) {
#pragma unroll
      for (int q = 0; q < 8; ++q) {
        int qq = g * 8 + q;
        lz[qq] = mask[(size_t)kb[qq < kk ? qq : m] * NWORD + lw];
      }
    }
  }
}

__device__ __forceinline__ u64 far_consume(const u64* __restrict__ mask,
                                           const int* __restrict__ kb, int kk, int lw,
                                           const u64 (&lz)[32]) {
  u64 v = 0;
#pragma unroll
  for (int g = 0; g < 4; ++g) {
    if (kk > g * 8) {
#pragma unroll
      for (int q = 0; q < 8; ++q) v |= lz[g * 8 + q];
    }
  }
  for (int q0 = 32; q0 < kk; q0 += 8) {   // rare: kk > 32 (first chunks only)
    int m = kk - 1;
#pragma unroll
    for (int q = 0; q < 8; ++q) {
      int qq = q0 + q;
      v |= mask[(size_t)kb[qq < kk ? qq : m] * NWORD + lw];
    }
  }
  return v;
}

// Blocked greedy NMS v4: every mask load gets >= 1 chunk of slack.
//  - wave0: ballot-based serial decision (no shfl roundtrip), diag prefetched 1 ahead.
//  - waves 1..3: spec paths, wave k combines keeps(c) -> word c+k at P2(c) using
//    R(c, c+k) preloaded at P0(c-1).
//  - far path: keeps(a) -> words >= a+4; loads issued at P2(a+1), consumed at
//    P2(a+2) (full chunk of slack), 32 prefetch regs ping-pong + inline fallback.
__global__ void __launch_bounds__(256) k_nms(const u64* __restrict__ mask,
                                             const float4* __restrict__ props,
                                             float* __restrict__ out) {
  __shared__ u64 rem[NWORD];
  __shared__ int keepb[K_POST];
  __shared__ int kept[3][64];
  __shared__ int s_kk[3];
  __shared__ u64 s_km[2];
  __shared__ int s_nk;
  int tid = threadIdx.x;
  int lane = tid & 63;
  int wave = tid >> 6;
  for (int w = tid; w < NWORD; w += 256) {
    int base = w * 64;
    u64 v;
    if (base + 64 <= K_PRE) v = 0ull;
    else if (base >= K_PRE) v = ~0ull;
    else v = (~0ull) << (K_PRE - base);
    rem[w] = v;
  }
  if (tid == 0) {
    s_nk = 0; s_kk[0] = 0; s_kk[1] = 0; s_kk[2] = 0; s_km[0] = 0; s_km[1] = 0;
  }
  __syncthreads();

  u64 diagA = 0, diagB = 0;
  u64 specA = 0, specB = 0;
  u64 lzA[32], lzB[32];
#pragma unroll
  for (int q = 0; q < 32; ++q) { lzA[q] = 0; lzB[q] = 0; }

  if (wave == 0) diagA = mask[(size_t)lane * NWORD + 0];
  else specA = mask[(size_t)lane * NWORD + wave];     // R(0, wave)
  int nk_reg = 0;

  for (int c = 0; c < NWORD; ++c) {
    if (s_nk >= K_POST) break;
    // ---- P0 ----
    if (wave == 0) {
      if (c + 1 < NWORD)
        diagB = mask[(size_t)(((c + 1) << 6) | lane) * NWORD + (c + 1)];
      u64 w = ~rem[c];
      u64 myrow = diagA;
      int nk = s_nk;
      int kk = 0;
      u64 km = 0;
      while (w && nk < K_POST) {
        int j = (int)__builtin_ctzll(w);
        if (lane == 0) { keepb[nk] = (c << 6) | j; kept[c % 3][kk] = (c << 6) | j; }
        km |= (1ull << j);
        nk++; kk++;
        u64 sup = __ballot((int)((myrow >> j) & 1ull));
        w &= ~sup;
        w &= ~(1ull << j);
      }
      if (lane == 0) { s_kk[c % 3] = kk; s_km[c & 1] = km; }
      nk_reg = nk;
    } else {
      if (c + 1 < NWORD && c + 1 + wave < NWORD)
        specB = mask[(size_t)(((c + 1) << 6) | lane) * NWORD + (c + 1 + wave)];
    }
    __syncthreads();   // barrier1
    // ---- P2 ----
    if (wave >= 1) {
      // spec combine: keeps(c) -> word c+wave
      if (c + wave < NWORD) {
        u64 km = s_km[c & 1];
        u64 v = ((km >> lane) & 1ull) ? specA : 0ull;
        for (int off = 32; off; off >>= 1) v |= __shfl_xor(v, off);
        if (lane == 0 && v) atomicOr(&rem[c + wave], v);
      }
      specA = specB;
      // far consume: keeps(c-2) -> word c+2+(tid-64)
      int lwC = c + 2 + (tid - 64);
      if (c >= 2 && lwC < NWORD) {
        int kkC = s_kk[(c - 2) % 3];
        if (kkC > 0) {
          u64 v = (c & 1) ? far_consume(mask, kept[(c - 2) % 3], kkC, lwC, lzB)
                          : far_consume(mask, kept[(c - 2) % 3], kkC, lwC, lzA);
          if (v) atomicOr(&rem[lwC], v);
        }
      }
      // far issue: keeps(c-1) -> word c+3+(tid-64) (consumed next chunk)
      int lwI = c + 3 + (tid - 64);
      if (c >= 1 && lwI < NWORD) {
        int kkI = s_kk[(c - 1) % 3];
        if (kkI > 0) {
          if (c & 1) far_issue(mask, kept[(c - 1) % 3], kkI, lwI, lzA);
          else       far_issue(mask, kept[(c - 1) % 3], kkI, lwI, lzB);
        }
      }
    } else {
      diagA = diagB;
    }
    if (tid == 0) s_nk = nk_reg;
    __syncthreads();   // barrier2
  }
  int nk = s_nk;
  for (int t = tid; t < K_POST; t += 256) {
    int kidx = (t < nk) ? keepb[t] : 0;   // exhausted: argmax over -inf -> 0
    float4 b = props[kidx];
    out[t * 5 + 0] = 0.0f;
    out[t * 5 + 1] = b.x;
    out[t * 5 + 2] = b.y;
    out[t * 5 + 3] = b.z;
    out[t * 5 + 4] = b.w;
  }
}

extern "C" void kernel_launch(void* const* d_in, const int* in_sizes, int n_in,
                              void* d_out, int out_size, void* d_ws, size_t ws_size,
                              hipStream_t stream) {
  const float* cls  = (const float*)d_in[0];
  const float* bbox = (const float*)d_in[1];
  float* out = (float*)d_out;
  char* ws = (char*)d_ws;

  u64* mask    = (u64*)ws;                    // [0, 18096128) u64[12032*188]
  u32* keys    = (u32*)ws;                    // [0, 9437184) overlays mask (dead before k_mask)
  u32* ctl     = (u32*)(ws + 9437184);
  u32* hist    = (u32*)(ws + 9437248);
  int* sel     = (int*)(ws + 9438464);
  int* tie     = (int*)(ws + 9486592);
  u64* comps   = (u64*)(ws + 18096128);
  float4* props= (float4*)(ws + 18240512);
  float* areas = (float*)(ws + 18433024);

  k_scores<<<dim3((N_ANCH + 255) / 256), dim3(256), 0, stream>>>(cls, bbox, keys);
  k_ctl_init<<<dim3(1), dim3(256), 0, stream>>>(ctl, hist);
  const int shifts[4] = {24, 16, 8, 0};
  for (int s = 0; s < 4; ++s)
    k_histscan<<<dim3(1024), dim3(256), 0, stream>>>(keys, ctl, hist, shifts[s], s);
  k_collect<<<dim3(1024), dim3(256), 0, stream>>>(keys, ctl, sel, tie);
  k_tiepick<<<dim3(1), dim3(256), 0, stream>>>(ctl, tie, sel);
  k_build<<<dim3(47), dim3(256), 0, stream>>>(keys, sel, comps);
  k_rankdec<<<dim3(375), dim3(256), 0, stream>>>(comps, sel, bbox, props, areas);
  k_mask<<<dim3(188, 188), dim3(64), 0, stream>>>(props, areas, mask);
  k_nms<<<dim3(1), dim3(256), 0, stream>>>(mask, props, out);
}